// Round 1
// baseline (5633.942 us; speedup 1.0000x reference)
//
#include <hip/hip_runtime.h>

// DHCF layer: e = embed_w[x]; agg = scatter_add(vals * e[col] -> row);
// m1 = dropout(agg + e, mask = jax threefry key(42), keep=0.9);
// x1 = leaky_relu(m1 @ fc_w.T + fc_b, 0.2); out = concat(e, x1) row-major [N, 256].
//
// Layout trick: out[:, :128] = e, out[:, 128:256] used as the m1 accumulator
// (init to e for the residual, scatter-add atomics, then FC overwrites in place).

#define NN 100000
#define DD 128
#define EE 3200000

__device__ __forceinline__ unsigned rotl32(unsigned v, int s) {
    return (v << s) | (v >> (32 - s));
}

// JAX threefry2x32, partitionable mode (modern JAX default):
// per-element block (x0=hi(idx)=0, x1=lo(idx)=idx), key (0, 42),
// output bits = out0 ^ out1; uniform = bitcast((bits>>9)|0x3f800000) - 1.
__device__ __forceinline__ bool keep_elem(unsigned idx) {
    unsigned x0 = 0u, x1 = idx;
    const unsigned k0 = 0u, k1 = 42u;
    const unsigned k2 = 0x1BD11BDAu ^ k0 ^ k1;
    x0 += k0; x1 += k1;
#define TFROUND(s) x0 += x1; x1 = rotl32(x1, s); x1 ^= x0;
    TFROUND(13) TFROUND(15) TFROUND(26) TFROUND(6)
    x0 += k1; x1 += k2 + 1u;
    TFROUND(17) TFROUND(29) TFROUND(16) TFROUND(24)
    x0 += k2; x1 += k0 + 2u;
    TFROUND(13) TFROUND(15) TFROUND(26) TFROUND(6)
    x0 += k0; x1 += k1 + 3u;
    TFROUND(17) TFROUND(29) TFROUND(16) TFROUND(24)
    x0 += k1; x1 += k2 + 4u;
    TFROUND(13) TFROUND(15) TFROUND(26) TFROUND(6)
    x0 += k2; x1 += k0 + 5u;
#undef TFROUND
    unsigned bits = x0 ^ x1;
    float u = __uint_as_float((bits >> 9) | 0x3f800000u) - 1.0f;
    return u < 0.9f;
}

// out[:, :128] = e ; out[:, 128:256] = e (residual base for scatter)
__global__ __launch_bounds__(256) void init_kernel(const int* __restrict__ x,
                                                   const float4* __restrict__ emb4,
                                                   float4* __restrict__ out4) {
    int i = blockIdx.x * 256 + threadIdx.x;   // one float4 (of 32) of one row
    int n = i >> 5;
    int q = i & 31;
    if (n >= NN) return;
    float4 v = emb4[(long)x[n] * 32 + q];
    out4[(long)n * 64 + q] = v;
    out4[(long)n * 64 + 32 + q] = v;
}

// one half-wave (32 lanes) per edge, 8 edges per group:
// out[row, 128+d] += vals * e[col, d]
#define EDGES_PER_GROUP 8
__global__ __launch_bounds__(256) void scatter_kernel(const int* __restrict__ x,
                                                      const int* __restrict__ row,
                                                      const int* __restrict__ col,
                                                      const float* __restrict__ vals,
                                                      const float4* __restrict__ emb4,
                                                      float* __restrict__ out) {
    long gid = (long)blockIdx.x * 256 + threadIdx.x;
    long group = gid >> 5;
    int lane = (int)(gid & 31);
    long e0 = group * EDGES_PER_GROUP;
#pragma unroll
    for (int k = 0; k < EDGES_PER_GROUP; ++k) {
        long e = e0 + k;
        if (e >= EE) break;
        int r = row[e];
        int c = col[e];
        float v = vals[e];
        float4 ev = emb4[(long)x[c] * 32 + lane];
        float* dst = out + (long)r * 256 + 128 + lane * 4;
        atomicAdd(dst + 0, v * ev.x);
        atomicAdd(dst + 1, v * ev.y);
        atomicAdd(dst + 2, v * ev.z);
        atomicAdd(dst + 3, v * ev.w);
    }
}

// 32 rows per block; dropout applied on m1 load; fc_w staged transposed in LDS.
__global__ __launch_bounds__(256) void fc_kernel(float* __restrict__ out,
                                                 const float* __restrict__ fc_w,
                                                 const float* __restrict__ fc_b) {
    __shared__ float wt[128][132];   // wt[k][j] = fc_w[j][k]; pad 132 keeps rows 16B-aligned
    __shared__ float ms[32][128];    // m1 tile after dropout
    int tid = threadIdx.x;
    int row0 = blockIdx.x * 32;

    for (int i = tid; i < 128 * 128; i += 256) {   // transpose-load fc_w
        int j = i >> 7, k = i & 127;
        wt[k][j] = fc_w[i];
    }
    for (int i = tid; i < 32 * 32; i += 256) {     // m1 tile (float4) + dropout
        int r = i >> 5, q = i & 31;
        long n = row0 + r;
        float4 v = *(const float4*)(out + n * 256 + 128 + q * 4);
        unsigned base = (unsigned)n * 128u + (unsigned)(q * 4);
        float* vp = reinterpret_cast<float*>(&v);
#pragma unroll
        for (int c = 0; c < 4; ++c)
            vp[c] = keep_elem(base + c) ? vp[c] * (1.0f / 0.9f) : 0.0f;
        *(float4*)(&ms[r][q * 4]) = v;
    }
    __syncthreads();

    int rg = tid >> 5;   // 0..7  -> rows rg*4 .. rg*4+3
    int cg = tid & 31;   // 0..31 -> cols cg*4 .. cg*4+3
    float acc[4][4] = {{0.f}};
    for (int k = 0; k < 128; ++k) {
        float4 w4 = *(const float4*)(&wt[k][cg * 4]);
#pragma unroll
        for (int r = 0; r < 4; ++r) {
            float m = ms[rg * 4 + r][k];
            acc[r][0] += m * w4.x;
            acc[r][1] += m * w4.y;
            acc[r][2] += m * w4.z;
            acc[r][3] += m * w4.w;
        }
    }

    float4 b4 = *(const float4*)(fc_b + cg * 4);
#pragma unroll
    for (int r = 0; r < 4; ++r) {
        long n = row0 + rg * 4 + r;
        float4 o;
        o.x = acc[r][0] + b4.x;
        o.y = acc[r][1] + b4.y;
        o.z = acc[r][2] + b4.z;
        o.w = acc[r][3] + b4.w;
        o.x = o.x >= 0.f ? o.x : 0.2f * o.x;
        o.y = o.y >= 0.f ? o.y : 0.2f * o.y;
        o.z = o.z >= 0.f ? o.z : 0.2f * o.z;
        o.w = o.w >= 0.f ? o.w : 0.2f * o.w;
        *(float4*)(out + n * 256 + 128 + cg * 4) = o;
    }
}

extern "C" void kernel_launch(void* const* d_in, const int* in_sizes, int n_in,
                              void* d_out, int out_size, void* d_ws, size_t ws_size,
                              hipStream_t stream) {
    const int*   x     = (const int*)d_in[0];
    const int*   row   = (const int*)d_in[1];
    const int*   col   = (const int*)d_in[2];
    const float* vals  = (const float*)d_in[3];
    const float* emb   = (const float*)d_in[4];
    const float* fc_w  = (const float*)d_in[5];
    const float* fc_b  = (const float*)d_in[6];
    float* out = (float*)d_out;

    init_kernel<<<(NN * 32 + 255) / 256, 256, 0, stream>>>(x, (const float4*)emb, (float4*)out);

    // E/EDGES_PER_GROUP groups * 32 lanes / 256 threads
    int scatter_blocks = (int)(((long)EE / EDGES_PER_GROUP) * 32 / 256);
    scatter_kernel<<<scatter_blocks, 256, 0, stream>>>(x, row, col, vals,
                                                       (const float4*)emb, out);

    fc_kernel<<<NN / 32, 256, 0, stream>>>(out, fc_w, fc_b);
}

// Round 2
// 863.287 us; speedup vs baseline: 6.5262x; 6.5262x over previous
//
#include <hip/hip_runtime.h>

// DHCF layer: e = embed_w[x]; agg = segment_sum(vals * e[col] -> row);
// m1 = dropout(agg + e, jax threefry key(42), keep=0.9);
// x1 = leaky_relu(m1 @ fc_w.T + fc_b, 0.2); out = concat(e, x1), [N, 256] f32.
//
// R2: replace 409.6M f32 atomics (77 G atomic/s serialization, VALUBusy 0.8%)
// with on-device CSR build + pull-gather (one wave per row, float2 per lane).

#define NN 100000
#define DD 128
#define EE 3200000
#define SCAN_B 256
#define NBLK ((NN + SCAN_B - 1) / SCAN_B)   // 391

__device__ __forceinline__ unsigned rotl32(unsigned v, int s) {
    return (v << s) | (v >> (32 - s));
}

// JAX threefry2x32, partitionable mode: block (0, idx), key (0, 42),
// bits = out0 ^ out1; u = bitcast((bits>>9)|0x3f800000)-1; keep = u < 0.9.
__device__ __forceinline__ bool keep_elem(unsigned idx) {
    unsigned x0 = 0u, x1 = idx;
    const unsigned k0 = 0u, k1 = 42u;
    const unsigned k2 = 0x1BD11BDAu ^ k0 ^ k1;
    x0 += k0; x1 += k1;
#define TFROUND(s) x0 += x1; x1 = rotl32(x1, s); x1 ^= x0;
    TFROUND(13) TFROUND(15) TFROUND(26) TFROUND(6)
    x0 += k1; x1 += k2 + 1u;
    TFROUND(17) TFROUND(29) TFROUND(16) TFROUND(24)
    x0 += k2; x1 += k0 + 2u;
    TFROUND(13) TFROUND(15) TFROUND(26) TFROUND(6)
    x0 += k0; x1 += k1 + 3u;
    TFROUND(17) TFROUND(29) TFROUND(16) TFROUND(24)
    x0 += k1; x1 += k2 + 4u;
    TFROUND(13) TFROUND(15) TFROUND(26) TFROUND(6)
    x0 += k2; x1 += k0 + 5u;
#undef TFROUND
    unsigned bits = x0 ^ x1;
    float u = __uint_as_float((bits >> 9) | 0x3f800000u) - 1.0f;
    return u < 0.9f;
}

// ---------------- CSR build ----------------

__global__ __launch_bounds__(256) void zero_kernel(int* __restrict__ counts) {
    int i = blockIdx.x * 256 + threadIdx.x;
    if (i < NN) counts[i] = 0;
}

__global__ __launch_bounds__(256) void hist_kernel(const int* __restrict__ row,
                                                   int* __restrict__ counts) {
    int e = blockIdx.x * 256 + threadIdx.x;
    if (e < EE) atomicAdd(&counts[row[e]], 1);
}

// per-256-block inclusive scan of counts -> rowptr[i+1]; block sums out.
__global__ __launch_bounds__(SCAN_B) void scan1_kernel(const int* __restrict__ counts,
                                                       int* __restrict__ rowptr,
                                                       int* __restrict__ bsums) {
    __shared__ int s[SCAN_B];
    int t = threadIdx.x;
    int i = blockIdx.x * SCAN_B + t;
    int v = (i < NN) ? counts[i] : 0;
    s[t] = v;
    __syncthreads();
    for (int d = 1; d < SCAN_B; d <<= 1) {
        int a = (t >= d) ? s[t - d] : 0;
        __syncthreads();
        s[t] += a;
        __syncthreads();
    }
    if (i < NN) rowptr[i + 1] = s[t];
    if (t == SCAN_B - 1) bsums[blockIdx.x] = s[t];
}

// exclusive scan of the 391 block sums (single block of 512).
__global__ __launch_bounds__(512) void scan2_kernel(int* __restrict__ bsums) {
    __shared__ int s[512];
    int t = threadIdx.x;
    int v = (t < NBLK) ? bsums[t] : 0;
    s[t] = v;
    __syncthreads();
    for (int d = 1; d < 512; d <<= 1) {
        int a = (t >= d) ? s[t - d] : 0;
        __syncthreads();
        s[t] += a;
        __syncthreads();
    }
    if (t < NBLK) bsums[t] = (t == 0) ? 0 : s[t] - v - (s[t] - s[t] ) + (t ? 0 : 0), // placeholder
        bsums[t] = (t == 0) ? 0 : s[t - 1 + 0] * 0 + (s[t] - v); // exclusive = inclusive - own
    __syncthreads();
}

__global__ __launch_bounds__(SCAN_B) void scan3_kernel(int* __restrict__ rowptr,
                                                       const int* __restrict__ bsums) {
    int i = blockIdx.x * SCAN_B + threadIdx.x;
    if (i < NN) rowptr[i + 1] += bsums[i >> 8];
    if (i == 0) rowptr[0] = 0;
}

// fill CSR slots: pos = rowptr[r+1] - atomicSub(counts[r], 1)  (old value).
__global__ __launch_bounds__(256) void csrfill_kernel(const int* __restrict__ row,
                                                      const int* __restrict__ col,
                                                      const float* __restrict__ vals,
                                                      const int* __restrict__ rowptr,
                                                      int* __restrict__ counts,
                                                      int* __restrict__ csr_ci,
                                                      float* __restrict__ csr_v) {
    int e = blockIdx.x * 256 + threadIdx.x;
    if (e >= EE) return;
    int r = row[e];
    int old = atomicSub(&counts[r], 1);
    int pos = rowptr[r + 1] - old;
    csr_ci[pos] = col[e];
    csr_v[pos] = vals[e];
}

// ---------------- pull gather: one wave per row ----------------
__global__ __launch_bounds__(256) void gather_kernel(const int* __restrict__ x,
                                                     const int* __restrict__ rowptr,
                                                     const int* __restrict__ csr_ci,
                                                     const float* __restrict__ csr_v,
                                                     const float2* __restrict__ emb2,
                                                     float2* __restrict__ out2) {
    int wave = threadIdx.x >> 6;
    int lane = threadIdx.x & 63;
    int n = blockIdx.x * 4 + wave;
    int s = rowptr[n], e = rowptr[n + 1];
    float2 acc = {0.f, 0.f};
    int j = s;
    for (; j + 4 <= e; j += 4) {
        int c0 = csr_ci[j], c1 = csr_ci[j + 1], c2 = csr_ci[j + 2], c3 = csr_ci[j + 3];
        float v0 = csr_v[j], v1 = csr_v[j + 1], v2 = csr_v[j + 2], v3 = csr_v[j + 3];
        int x0 = x[c0], x1 = x[c1], x2 = x[c2], x3 = x[c3];
        float2 e0 = emb2[(long)x0 * 64 + lane];
        float2 e1 = emb2[(long)x1 * 64 + lane];
        float2 e2 = emb2[(long)x2 * 64 + lane];
        float2 e3 = emb2[(long)x3 * 64 + lane];
        acc.x += v0 * e0.x + v1 * e1.x + v2 * e2.x + v3 * e3.x;
        acc.y += v0 * e0.y + v1 * e1.y + v2 * e2.y + v3 * e3.y;
    }
    for (; j < e; ++j) {
        int c = csr_ci[j];
        float v = csr_v[j];
        float2 ev = emb2[(long)x[c] * 64 + lane];
        acc.x += v * ev.x;
        acc.y += v * ev.y;
    }
    float2 es = emb2[(long)x[n] * 64 + lane];
    out2[(long)n * 128 + lane] = es;                          // out[:, :128] = e
    float2 m1;
    m1.x = acc.x + es.x;
    m1.y = acc.y + es.y;
    out2[(long)n * 128 + 64 + lane] = m1;                     // out[:, 128:] = agg + e
}

// ---------------- fallback path (R1, proven) ----------------
__global__ __launch_bounds__(256) void init_kernel(const int* __restrict__ x,
                                                   const float4* __restrict__ emb4,
                                                   float4* __restrict__ out4) {
    int i = blockIdx.x * 256 + threadIdx.x;
    int n = i >> 5;
    int q = i & 31;
    if (n >= NN) return;
    float4 v = emb4[(long)x[n] * 32 + q];
    out4[(long)n * 64 + q] = v;
    out4[(long)n * 64 + 32 + q] = v;
}

#define EDGES_PER_GROUP 8
__global__ __launch_bounds__(256) void scatter_kernel(const int* __restrict__ x,
                                                      const int* __restrict__ row,
                                                      const int* __restrict__ col,
                                                      const float* __restrict__ vals,
                                                      const float4* __restrict__ emb4,
                                                      float* __restrict__ out) {
    long gid = (long)blockIdx.x * 256 + threadIdx.x;
    long group = gid >> 5;
    int lane = (int)(gid & 31);
    long e0 = group * EDGES_PER_GROUP;
#pragma unroll
    for (int k = 0; k < EDGES_PER_GROUP; ++k) {
        long e = e0 + k;
        if (e >= EE) break;
        int r = row[e];
        int c = col[e];
        float v = vals[e];
        float4 ev = emb4[(long)x[c] * 32 + lane];
        float* dst = out + (long)r * 256 + 128 + lane * 4;
        atomicAdd(dst + 0, v * ev.x);
        atomicAdd(dst + 1, v * ev.y);
        atomicAdd(dst + 2, v * ev.z);
        atomicAdd(dst + 3, v * ev.w);
    }
}

// ---------------- FC + dropout + leaky_relu (unchanged from R1) ----------------
__global__ __launch_bounds__(256) void fc_kernel(float* __restrict__ out,
                                                 const float* __restrict__ fc_w,
                                                 const float* __restrict__ fc_b) {
    __shared__ float wt[128][132];
    __shared__ float ms[32][128];
    int tid = threadIdx.x;
    int row0 = blockIdx.x * 32;

    for (int i = tid; i < 128 * 128; i += 256) {
        int j = i >> 7, k = i & 127;
        wt[k][j] = fc_w[i];
    }
    for (int i = tid; i < 32 * 32; i += 256) {
        int r = i >> 5, q = i & 31;
        long n = row0 + r;
        float4 v = *(const float4*)(out + n * 256 + 128 + q * 4);
        unsigned base = (unsigned)n * 128u + (unsigned)(q * 4);
        float* vp = reinterpret_cast<float*>(&v);
#pragma unroll
        for (int c = 0; c < 4; ++c)
            vp[c] = keep_elem(base + c) ? vp[c] * (1.0f / 0.9f) : 0.0f;
        *(float4*)(&ms[r][q * 4]) = v;
    }
    __syncthreads();

    int rg = tid >> 5;
    int cg = tid & 31;
    float acc[4][4] = {{0.f}};
    for (int k = 0; k < 128; ++k) {
        float4 w4 = *(const float4*)(&wt[k][cg * 4]);
#pragma unroll
        for (int r = 0; r < 4; ++r) {
            float m = ms[rg * 4 + r][k];
            acc[r][0] += m * w4.x;
            acc[r][1] += m * w4.y;
            acc[r][2] += m * w4.z;
            acc[r][3] += m * w4.w;
        }
    }

    float4 b4 = *(const float4*)(fc_b + cg * 4);
#pragma unroll
    for (int r = 0; r < 4; ++r) {
        long n = row0 + rg * 4 + r;
        float4 o;
        o.x = acc[r][0] + b4.x;
        o.y = acc[r][1] + b4.y;
        o.z = acc[r][2] + b4.z;
        o.w = acc[r][3] + b4.w;
        o.x = o.x >= 0.f ? o.x : 0.2f * o.x;
        o.y = o.y >= 0.f ? o.y : 0.2f * o.y;
        o.z = o.z >= 0.f ? o.z : 0.2f * o.z;
        o.w = o.w >= 0.f ? o.w : 0.2f * o.w;
        *(float4*)(out + n * 256 + 128 + cg * 4) = o;
    }
}

extern "C" void kernel_launch(void* const* d_in, const int* in_sizes, int n_in,
                              void* d_out, int out_size, void* d_ws, size_t ws_size,
                              hipStream_t stream) {
    const int*   x    = (const int*)d_in[0];
    const int*   row  = (const int*)d_in[1];
    const int*   col  = (const int*)d_in[2];
    const float* vals = (const float*)d_in[3];
    const float* emb  = (const float*)d_in[4];
    const float* fc_w = (const float*)d_in[5];
    const float* fc_b = (const float*)d_in[6];
    float* out = (float*)d_out;

    // workspace layout
    size_t off = 0;
    char* ws = (char*)d_ws;
    int* counts = (int*)(ws + off); off += (((size_t)NN * 4) + 255) & ~(size_t)255;
    int* rowptr = (int*)(ws + off); off += (((size_t)(NN + 1) * 4) + 255) & ~(size_t)255;
    int* bsums  = (int*)(ws + off); off += 4096;
    int* csr_ci = (int*)(ws + off); off += (size_t)EE * 4;
    float* csr_v = (float*)(ws + off); off += (size_t)EE * 4;
    bool use_csr = (ws_size >= off);

    if (use_csr) {
        zero_kernel<<<(NN + 255) / 256, 256, 0, stream>>>(counts);
        hist_kernel<<<(EE + 255) / 256, 256, 0, stream>>>(row, counts);
        scan1_kernel<<<NBLK, SCAN_B, 0, stream>>>(counts, rowptr, bsums);
        scan2_kernel<<<1, 512, 0, stream>>>(bsums);
        scan3_kernel<<<NBLK, SCAN_B, 0, stream>>>(rowptr, bsums);
        csrfill_kernel<<<(EE + 255) / 256, 256, 0, stream>>>(row, col, vals, rowptr,
                                                             counts, csr_ci, csr_v);
        gather_kernel<<<NN / 4, 256, 0, stream>>>(x, rowptr, csr_ci, csr_v,
                                                  (const float2*)emb, (float2*)out);
    } else {
        init_kernel<<<(NN * 32 + 255) / 256, 256, 0, stream>>>(x, (const float4*)emb, (float4*)out);
        int scatter_blocks = (int)(((long)EE / EDGES_PER_GROUP) * 32 / 256);
        scatter_kernel<<<scatter_blocks, 256, 0, stream>>>(x, row, col, vals,
                                                           (const float4*)emb, out);
    }

    fc_kernel<<<NN / 32, 256, 0, stream>>>(out, fc_w, fc_b);
}

// Round 3
// 740.175 us; speedup vs baseline: 7.6116x; 1.1663x over previous
//
#include <hip/hip_runtime.h>

// DHCF layer: e = embed_w[x]; agg = segment_sum(vals * e[col] -> row);
// m1 = dropout(agg + e, jax threefry key(42), keep=0.9);
// x1 = leaky_relu(m1 @ fc_w.T + fc_b, 0.2); out = concat(e, x1), [N, 256] f32.
//
// R3: gather is L2-miss-line-rate bound (815 MB FETCH = 50% of 1.64 GB stream).
// (a) bf16 embedding copy in ws halves gather lines/bytes;
// (b) csrfill packs (x[col], val) into one aligned 8B slot (1 scattered store, not 2).

#define NN 100000
#define DD 128
#define EE 3200000
#define SCAN_B 256
#define NBLK ((NN + SCAN_B - 1) / SCAN_B)   // 391

__device__ __forceinline__ unsigned rotl32(unsigned v, int s) {
    return (v << s) | (v >> (32 - s));
}

// JAX threefry2x32, partitionable mode: block (0, idx), key (0, 42),
// bits = out0 ^ out1; u = bitcast((bits>>9)|0x3f800000)-1; keep = u < 0.9.
__device__ __forceinline__ bool keep_elem(unsigned idx) {
    unsigned x0 = 0u, x1 = idx;
    const unsigned k0 = 0u, k1 = 42u;
    const unsigned k2 = 0x1BD11BDAu ^ k0 ^ k1;
    x0 += k0; x1 += k1;
#define TFROUND(s) x0 += x1; x1 = rotl32(x1, s); x1 ^= x0;
    TFROUND(13) TFROUND(15) TFROUND(26) TFROUND(6)
    x0 += k1; x1 += k2 + 1u;
    TFROUND(17) TFROUND(29) TFROUND(16) TFROUND(24)
    x0 += k2; x1 += k0 + 2u;
    TFROUND(13) TFROUND(15) TFROUND(26) TFROUND(6)
    x0 += k0; x1 += k1 + 3u;
    TFROUND(17) TFROUND(29) TFROUND(16) TFROUND(24)
    x0 += k1; x1 += k2 + 4u;
    TFROUND(13) TFROUND(15) TFROUND(26) TFROUND(6)
    x0 += k2; x1 += k0 + 5u;
#undef TFROUND
    unsigned bits = x0 ^ x1;
    float u = __uint_as_float((bits >> 9) | 0x3f800000u) - 1.0f;
    return u < 0.9f;
}

// ---------------- CSR build ----------------

__global__ __launch_bounds__(256) void zero_kernel(int* __restrict__ counts) {
    int i = blockIdx.x * 256 + threadIdx.x;
    if (i < NN) counts[i] = 0;
}

__global__ __launch_bounds__(256) void hist_kernel(const int* __restrict__ row,
                                                   int* __restrict__ counts) {
    int e = blockIdx.x * 256 + threadIdx.x;
    if (e < EE) atomicAdd(&counts[row[e]], 1);
}

// per-256-block inclusive scan of counts -> rowptr[i+1]; block sums out.
__global__ __launch_bounds__(SCAN_B) void scan1_kernel(const int* __restrict__ counts,
                                                       int* __restrict__ rowptr,
                                                       int* __restrict__ bsums) {
    __shared__ int s[SCAN_B];
    int t = threadIdx.x;
    int i = blockIdx.x * SCAN_B + t;
    int v = (i < NN) ? counts[i] : 0;
    s[t] = v;
    __syncthreads();
    for (int d = 1; d < SCAN_B; d <<= 1) {
        int a = (t >= d) ? s[t - d] : 0;
        __syncthreads();
        s[t] += a;
        __syncthreads();
    }
    if (i < NN) rowptr[i + 1] = s[t];
    if (t == SCAN_B - 1) bsums[blockIdx.x] = s[t];
}

// exclusive scan of the 391 block sums (single block of 512): excl = incl - own.
__global__ __launch_bounds__(512) void scan2_kernel(int* __restrict__ bsums) {
    __shared__ int s[512];
    int t = threadIdx.x;
    int v = (t < NBLK) ? bsums[t] : 0;
    s[t] = v;
    __syncthreads();
    for (int d = 1; d < 512; d <<= 1) {
        int a = (t >= d) ? s[t - d] : 0;
        __syncthreads();
        s[t] += a;
        __syncthreads();
    }
    if (t < NBLK) bsums[t] = s[t] - v;
}

__global__ __launch_bounds__(SCAN_B) void scan3_kernel(int* __restrict__ rowptr,
                                                       const int* __restrict__ bsums) {
    int i = blockIdx.x * SCAN_B + threadIdx.x;
    if (i < NN) rowptr[i + 1] += bsums[i >> 8];
    if (i == 0) rowptr[0] = 0;
}

// fill CSR: pos = rowptr[r+1] - atomicSub(counts[r],1); slot = (x[col] | val<<32).
__global__ __launch_bounds__(256) void csrfill_kernel(const int* __restrict__ x,
                                                      const int* __restrict__ row,
                                                      const int* __restrict__ col,
                                                      const float* __restrict__ vals,
                                                      const int* __restrict__ rowptr,
                                                      int* __restrict__ counts,
                                                      unsigned long long* __restrict__ csr) {
    int e = blockIdx.x * 256 + threadIdx.x;
    if (e >= EE) return;
    int r = row[e];
    int old = atomicSub(&counts[r], 1);
    int pos = rowptr[r + 1] - old;
    unsigned xc = (unsigned)x[col[e]];
    unsigned vb = __float_as_uint(vals[e]);
    csr[pos] = (unsigned long long)xc | ((unsigned long long)vb << 32);
}

// f32 -> bf16(RNE) copy of the embedding table; one uint (2 elems) per thread.
__global__ __launch_bounds__(256) void cvt_kernel(const float2* __restrict__ emb2,
                                                  unsigned* __restrict__ ebf) {
    long i = (long)blockIdx.x * 256 + threadIdx.x;
    if (i >= (long)NN * 64) return;
    float2 v = emb2[i];
    unsigned a = __float_as_uint(v.x), b = __float_as_uint(v.y);
    a = (a + 0x7fffu + ((a >> 16) & 1u)) >> 16;
    b = (b + 0x7fffu + ((b >> 16) & 1u)) >> 16;
    ebf[i] = a | (b << 16);
}

// ---------------- pull gather (bf16 table): one wave per row ----------------
__global__ __launch_bounds__(256) void gather_bf16_kernel(const int* __restrict__ x,
                                                          const int* __restrict__ rowptr,
                                                          const unsigned long long* __restrict__ csr,
                                                          const unsigned* __restrict__ ebf,
                                                          const float2* __restrict__ emb2,
                                                          float2* __restrict__ out2) {
    int wave = threadIdx.x >> 6;
    int lane = threadIdx.x & 63;
    int n = blockIdx.x * 4 + wave;
    int s = rowptr[n], e = rowptr[n + 1];
    float ax = 0.f, ay = 0.f;
    int j = s;
    for (; j + 4 <= e; j += 4) {
        unsigned long long p0 = csr[j], p1 = csr[j + 1], p2 = csr[j + 2], p3 = csr[j + 3];
        unsigned b0 = ebf[(long)(unsigned)p0 * 64 + lane];
        unsigned b1 = ebf[(long)(unsigned)p1 * 64 + lane];
        unsigned b2 = ebf[(long)(unsigned)p2 * 64 + lane];
        unsigned b3 = ebf[(long)(unsigned)p3 * 64 + lane];
        float v0 = __uint_as_float((unsigned)(p0 >> 32));
        float v1 = __uint_as_float((unsigned)(p1 >> 32));
        float v2 = __uint_as_float((unsigned)(p2 >> 32));
        float v3 = __uint_as_float((unsigned)(p3 >> 32));
        ax += v0 * __uint_as_float(b0 << 16) + v1 * __uint_as_float(b1 << 16)
            + v2 * __uint_as_float(b2 << 16) + v3 * __uint_as_float(b3 << 16);
        ay += v0 * __uint_as_float(b0 & 0xffff0000u) + v1 * __uint_as_float(b1 & 0xffff0000u)
            + v2 * __uint_as_float(b2 & 0xffff0000u) + v3 * __uint_as_float(b3 & 0xffff0000u);
    }
    for (; j < e; ++j) {
        unsigned long long p = csr[j];
        unsigned b = ebf[(long)(unsigned)p * 64 + lane];
        float v = __uint_as_float((unsigned)(p >> 32));
        ax += v * __uint_as_float(b << 16);
        ay += v * __uint_as_float(b & 0xffff0000u);
    }
    float2 es = emb2[(long)x[n] * 64 + lane];   // f32 row: exact residual + e-output
    out2[(long)n * 128 + lane] = es;
    float2 m1;
    m1.x = ax + es.x;
    m1.y = ay + es.y;
    out2[(long)n * 128 + 64 + lane] = m1;
}

// ---------------- pull gather (f32 table) — ws-too-small tier ----------------
__global__ __launch_bounds__(256) void gather_f32_kernel(const int* __restrict__ x,
                                                         const int* __restrict__ rowptr,
                                                         const unsigned long long* __restrict__ csr,
                                                         const float2* __restrict__ emb2,
                                                         float2* __restrict__ out2) {
    int wave = threadIdx.x >> 6;
    int lane = threadIdx.x & 63;
    int n = blockIdx.x * 4 + wave;
    int s = rowptr[n], e = rowptr[n + 1];
    float2 acc = {0.f, 0.f};
    int j = s;
    for (; j + 4 <= e; j += 4) {
        unsigned long long p0 = csr[j], p1 = csr[j + 1], p2 = csr[j + 2], p3 = csr[j + 3];
        float2 e0 = emb2[(long)(unsigned)p0 * 64 + lane];
        float2 e1 = emb2[(long)(unsigned)p1 * 64 + lane];
        float2 e2 = emb2[(long)(unsigned)p2 * 64 + lane];
        float2 e3 = emb2[(long)(unsigned)p3 * 64 + lane];
        float v0 = __uint_as_float((unsigned)(p0 >> 32));
        float v1 = __uint_as_float((unsigned)(p1 >> 32));
        float v2 = __uint_as_float((unsigned)(p2 >> 32));
        float v3 = __uint_as_float((unsigned)(p3 >> 32));
        acc.x += v0 * e0.x + v1 * e1.x + v2 * e2.x + v3 * e3.x;
        acc.y += v0 * e0.y + v1 * e1.y + v2 * e2.y + v3 * e3.y;
    }
    for (; j < e; ++j) {
        unsigned long long p = csr[j];
        float2 ev = emb2[(long)(unsigned)p * 64 + lane];
        float v = __uint_as_float((unsigned)(p >> 32));
        acc.x += v * ev.x;
        acc.y += v * ev.y;
    }
    float2 es = emb2[(long)x[n] * 64 + lane];
    out2[(long)n * 128 + lane] = es;
    float2 m1;
    m1.x = acc.x + es.x;
    m1.y = acc.y + es.y;
    out2[(long)n * 128 + 64 + lane] = m1;
}

// ---------------- FC + dropout + leaky_relu ----------------
__global__ __launch_bounds__(256) void fc_kernel(float* __restrict__ out,
                                                 const float* __restrict__ fc_w,
                                                 const float* __restrict__ fc_b) {
    __shared__ float wt[128][132];
    __shared__ float ms[32][128];
    int tid = threadIdx.x;
    int row0 = blockIdx.x * 32;

    for (int i = tid; i < 128 * 128; i += 256) {
        int j = i >> 7, k = i & 127;
        wt[k][j] = fc_w[i];
    }
    for (int i = tid; i < 32 * 32; i += 256) {
        int r = i >> 5, q = i & 31;
        long n = row0 + r;
        float4 v = *(const float4*)(out + n * 256 + 128 + q * 4);
        unsigned base = (unsigned)n * 128u + (unsigned)(q * 4);
        float* vp = reinterpret_cast<float*>(&v);
#pragma unroll
        for (int c = 0; c < 4; ++c)
            vp[c] = keep_elem(base + c) ? vp[c] * (1.0f / 0.9f) : 0.0f;
        *(float4*)(&ms[r][q * 4]) = v;
    }
    __syncthreads();

    int rg = tid >> 5;
    int cg = tid & 31;
    float acc[4][4] = {{0.f}};
    for (int k = 0; k < 128; ++k) {
        float4 w4 = *(const float4*)(&wt[k][cg * 4]);
#pragma unroll
        for (int r = 0; r < 4; ++r) {
            float m = ms[rg * 4 + r][k];
            acc[r][0] += m * w4.x;
            acc[r][1] += m * w4.y;
            acc[r][2] += m * w4.z;
            acc[r][3] += m * w4.w;
        }
    }

    float4 b4 = *(const float4*)(fc_b + cg * 4);
#pragma unroll
    for (int r = 0; r < 4; ++r) {
        long n = row0 + rg * 4 + r;
        float4 o;
        o.x = acc[r][0] + b4.x;
        o.y = acc[r][1] + b4.y;
        o.z = acc[r][2] + b4.z;
        o.w = acc[r][3] + b4.w;
        o.x = o.x >= 0.f ? o.x : 0.2f * o.x;
        o.y = o.y >= 0.f ? o.y : 0.2f * o.y;
        o.z = o.z >= 0.f ? o.z : 0.2f * o.z;
        o.w = o.w >= 0.f ? o.w : 0.2f * o.w;
        *(float4*)(out + n * 256 + 128 + cg * 4) = o;
    }
}

// ---------------- R1 atomic fallback (ws too small for CSR) ----------------
__global__ __launch_bounds__(256) void init_kernel(const int* __restrict__ x,
                                                   const float4* __restrict__ emb4,
                                                   float4* __restrict__ out4) {
    int i = blockIdx.x * 256 + threadIdx.x;
    int n = i >> 5;
    int q = i & 31;
    if (n >= NN) return;
    float4 v = emb4[(long)x[n] * 32 + q];
    out4[(long)n * 64 + q] = v;
    out4[(long)n * 64 + 32 + q] = v;
}

#define EDGES_PER_GROUP 8
__global__ __launch_bounds__(256) void scatter_kernel(const int* __restrict__ x,
                                                      const int* __restrict__ row,
                                                      const int* __restrict__ col,
                                                      const float* __restrict__ vals,
                                                      const float4* __restrict__ emb4,
                                                      float* __restrict__ out) {
    long gid = (long)blockIdx.x * 256 + threadIdx.x;
    long group = gid >> 5;
    int lane = (int)(gid & 31);
    long e0 = group * EDGES_PER_GROUP;
#pragma unroll
    for (int k = 0; k < EDGES_PER_GROUP; ++k) {
        long e = e0 + k;
        if (e >= EE) break;
        int r = row[e];
        int c = col[e];
        float v = vals[e];
        float4 ev = emb4[(long)x[c] * 32 + lane];
        float* dst = out + (long)r * 256 + 128 + lane * 4;
        atomicAdd(dst + 0, v * ev.x);
        atomicAdd(dst + 1, v * ev.y);
        atomicAdd(dst + 2, v * ev.z);
        atomicAdd(dst + 3, v * ev.w);
    }
}

extern "C" void kernel_launch(void* const* d_in, const int* in_sizes, int n_in,
                              void* d_out, int out_size, void* d_ws, size_t ws_size,
                              hipStream_t stream) {
    const int*   x    = (const int*)d_in[0];
    const int*   row  = (const int*)d_in[1];
    const int*   col  = (const int*)d_in[2];
    const float* vals = (const float*)d_in[3];
    const float* emb  = (const float*)d_in[4];
    const float* fc_w = (const float*)d_in[5];
    const float* fc_b = (const float*)d_in[6];
    float* out = (float*)d_out;

    size_t off = 0;
    char* ws = (char*)d_ws;
    int* counts = (int*)(ws + off); off += (((size_t)NN * 4) + 255) & ~(size_t)255;
    int* rowptr = (int*)(ws + off); off += (((size_t)(NN + 1) * 4) + 255) & ~(size_t)255;
    int* bsums  = (int*)(ws + off); off += 4096;
    unsigned long long* csr = (unsigned long long*)(ws + off); off += (size_t)EE * 8;
    size_t need_csr = off;
    unsigned* ebf = (unsigned*)(ws + off); off += (size_t)NN * DD * 2;
    size_t need_bf16 = off;

    if (ws_size >= need_csr) {
        zero_kernel<<<(NN + 255) / 256, 256, 0, stream>>>(counts);
        hist_kernel<<<(EE + 255) / 256, 256, 0, stream>>>(row, counts);
        scan1_kernel<<<NBLK, SCAN_B, 0, stream>>>(counts, rowptr, bsums);
        scan2_kernel<<<1, 512, 0, stream>>>(bsums);
        scan3_kernel<<<NBLK, SCAN_B, 0, stream>>>(rowptr, bsums);
        csrfill_kernel<<<(EE + 255) / 256, 256, 0, stream>>>(x, row, col, vals, rowptr,
                                                             counts, csr);
        if (ws_size >= need_bf16) {
            cvt_kernel<<<(int)(((long)NN * 64 + 255) / 256), 256, 0, stream>>>(
                (const float2*)emb, ebf);
            gather_bf16_kernel<<<NN / 4, 256, 0, stream>>>(x, rowptr, csr, ebf,
                                                           (const float2*)emb, (float2*)out);
        } else {
            gather_f32_kernel<<<NN / 4, 256, 0, stream>>>(x, rowptr, csr,
                                                          (const float2*)emb, (float2*)out);
        }
    } else {
        init_kernel<<<(NN * 32 + 255) / 256, 256, 0, stream>>>(x, (const float4*)emb, (float4*)out);
        int scatter_blocks = (int)(((long)EE / EDGES_PER_GROUP) * 32 / 256);
        scatter_kernel<<<scatter_blocks, 256, 0, stream>>>(x, row, col, vals,
                                                           (const float4*)emb, out);
    }

    fc_kernel<<<NN / 32, 256, 0, stream>>>(out, fc_w, fc_b);
}

// Round 4
// 658.870 us; speedup vs baseline: 8.5509x; 1.1234x over previous
//
#include <hip/hip_runtime.h>

// DHCF layer: e = embed_w[x]; agg = segment_sum(vals * e[col] -> row);
// m1 = dropout(agg + e, jax threefry key(42), keep=0.9);
// x1 = leaky_relu(m1 @ fc_w.T + fc_b, 0.2); out = concat(e, x1), [N, 256] f32.
//
// R4: csrfill was atomic-return-chain bound (187us, VALU 0.7%, 201MB writeback).
// (a) rank computed in hist (ILP-4 atomics), fill is atomic-free streaming;
// (b) CSR entry packed to 4B: [16:0]=x[col] (17b), [31:17]=val (sign+exp+6mant, RHU);
// (c) zero+cvt merged. ws layout byte-identical to R3's proven 52,004,608.

#define NN 100000
#define DD 128
#define EE 3200000
#define SCAN_B 256
#define NBLK ((NN + SCAN_B - 1) / SCAN_B)   // 391

__device__ __forceinline__ unsigned rotl32(unsigned v, int s) {
    return (v << s) | (v >> (32 - s));
}

// JAX threefry2x32, partitionable mode: block (0, idx), key (0, 42),
// bits = out0 ^ out1; u = bitcast((bits>>9)|0x3f800000)-1; keep = u < 0.9.
__device__ __forceinline__ bool keep_elem(unsigned idx) {
    unsigned x0 = 0u, x1 = idx;
    const unsigned k0 = 0u, k1 = 42u;
    const unsigned k2 = 0x1BD11BDAu ^ k0 ^ k1;
    x0 += k0; x1 += k1;
#define TFROUND(s) x0 += x1; x1 = rotl32(x1, s); x1 ^= x0;
    TFROUND(13) TFROUND(15) TFROUND(26) TFROUND(6)
    x0 += k1; x1 += k2 + 1u;
    TFROUND(17) TFROUND(29) TFROUND(16) TFROUND(24)
    x0 += k2; x1 += k0 + 2u;
    TFROUND(13) TFROUND(15) TFROUND(26) TFROUND(6)
    x0 += k0; x1 += k1 + 3u;
    TFROUND(17) TFROUND(29) TFROUND(16) TFROUND(24)
    x0 += k1; x1 += k2 + 4u;
    TFROUND(13) TFROUND(15) TFROUND(26) TFROUND(6)
    x0 += k2; x1 += k0 + 5u;
#undef TFROUND
    unsigned bits = x0 ^ x1;
    float u = __uint_as_float((bits >> 9) | 0x3f800000u) - 1.0f;
    return u < 0.9f;
}

// ---------------- setup: zero counts + f32->bf16 table convert ----------------
// grid 12500 x 256: thread i converts float4 -> 2 packed bf16 uints;
// threads < 25000 also zero counts (int4).
__global__ __launch_bounds__(256) void setup_kernel(const float4* __restrict__ emb4,
                                                    uint2* __restrict__ ebf2,
                                                    int4* __restrict__ counts4) {
    int i = blockIdx.x * 256 + threadIdx.x;          // 3.2M threads
    float4 v = emb4[i];
    unsigned a = __float_as_uint(v.x), b = __float_as_uint(v.y);
    unsigned c = __float_as_uint(v.z), d = __float_as_uint(v.w);
    a = (a + 0x7fffu + ((a >> 16) & 1u)) >> 16;
    b = (b + 0x7fffu + ((b >> 16) & 1u)) >> 16;
    c = (c + 0x7fffu + ((c >> 16) & 1u)) >> 16;
    d = (d + 0x7fffu + ((d >> 16) & 1u)) >> 16;
    uint2 o;
    o.x = a | (b << 16);
    o.y = c | (d << 16);
    ebf2[i] = o;
    if (i < NN / 4) counts4[i] = make_int4(0, 0, 0, 0);
}

// ---------------- hist: degree count + per-edge rank (ILP-4) ----------------
__global__ __launch_bounds__(256) void hist_kernel(const int4* __restrict__ row4,
                                                   int* __restrict__ counts,
                                                   int4* __restrict__ rank4) {
    int i = blockIdx.x * 256 + threadIdx.x;          // 800k threads (EE/4)
    int4 r = row4[i];
    int4 k;
    k.x = atomicAdd(&counts[r.x], 1);
    k.y = atomicAdd(&counts[r.y], 1);
    k.z = atomicAdd(&counts[r.z], 1);
    k.w = atomicAdd(&counts[r.w], 1);
    rank4[i] = k;
}

// per-256-block inclusive scan of counts -> rowptr[i+1]; block sums out.
__global__ __launch_bounds__(SCAN_B) void scan1_kernel(const int* __restrict__ counts,
                                                       int* __restrict__ rowptr,
                                                       int* __restrict__ bsums) {
    __shared__ int s[SCAN_B];
    int t = threadIdx.x;
    int i = blockIdx.x * SCAN_B + t;
    int v = (i < NN) ? counts[i] : 0;
    s[t] = v;
    __syncthreads();
    for (int d = 1; d < SCAN_B; d <<= 1) {
        int a = (t >= d) ? s[t - d] : 0;
        __syncthreads();
        s[t] += a;
        __syncthreads();
    }
    if (i < NN) rowptr[i + 1] = s[t];
    if (t == SCAN_B - 1) bsums[blockIdx.x] = s[t];
}

// exclusive scan of the 391 block sums: excl = incl - own.
__global__ __launch_bounds__(512) void scan2_kernel(int* __restrict__ bsums) {
    __shared__ int s[512];
    int t = threadIdx.x;
    int v = (t < NBLK) ? bsums[t] : 0;
    s[t] = v;
    __syncthreads();
    for (int d = 1; d < 512; d <<= 1) {
        int a = (t >= d) ? s[t - d] : 0;
        __syncthreads();
        s[t] += a;
        __syncthreads();
    }
    if (t < NBLK) bsums[t] = s[t] - v;
}

__global__ __launch_bounds__(SCAN_B) void scan3_kernel(int* __restrict__ rowptr,
                                                       const int* __restrict__ bsums) {
    int i = blockIdx.x * SCAN_B + threadIdx.x;
    if (i < NN) rowptr[i + 1] += bsums[i >> 8];
    if (i == 0) rowptr[0] = 0;
}

// ---------------- fill: atomic-free scattered pack-store (ILP-4) ----------------
// entry = (round(valbits)+trunc to sign+exp+6mant in [31:17]) | x[col] (17 bits).
__device__ __forceinline__ unsigned pack_entry(int xc, float v) {
    unsigned pb = __float_as_uint(v) + 0x10000u;     // round-half-up at bit 17
    return (pb & 0xFFFE0000u) | (unsigned)xc;
}

__global__ __launch_bounds__(256) void fill_kernel(const int* __restrict__ x,
                                                   const int4* __restrict__ row4,
                                                   const int4* __restrict__ col4,
                                                   const float4* __restrict__ vals4,
                                                   const int4* __restrict__ rank4,
                                                   const int* __restrict__ rowptr,
                                                   unsigned* __restrict__ csr) {
    int i = blockIdx.x * 256 + threadIdx.x;          // 800k threads
    int4 r = row4[i];
    int4 c = col4[i];
    float4 v = vals4[i];
    int4 k = rank4[i];
    csr[rowptr[r.x] + k.x] = pack_entry(x[c.x], v.x);
    csr[rowptr[r.y] + k.y] = pack_entry(x[c.y], v.y);
    csr[rowptr[r.z] + k.z] = pack_entry(x[c.z], v.z);
    csr[rowptr[r.w] + k.w] = pack_entry(x[c.w], v.w);
}

// ---------------- pull gather (bf16 table, 4B entries): one wave per row ----------------
__global__ __launch_bounds__(256) void gather_kernel(const int* __restrict__ x,
                                                     const int* __restrict__ rowptr,
                                                     const unsigned* __restrict__ csr,
                                                     const unsigned* __restrict__ ebf,
                                                     const float2* __restrict__ emb2,
                                                     float2* __restrict__ out2) {
    int wave = threadIdx.x >> 6;
    int lane = threadIdx.x & 63;
    int n = blockIdx.x * 4 + wave;
    int s = rowptr[n], e = rowptr[n + 1];
    float ax = 0.f, ay = 0.f;
    int j = s;
    for (; j + 4 <= e; j += 4) {
        unsigned p0 = csr[j], p1 = csr[j + 1], p2 = csr[j + 2], p3 = csr[j + 3];
        unsigned b0 = ebf[(long)(p0 & 0x1FFFFu) * 64 + lane];
        unsigned b1 = ebf[(long)(p1 & 0x1FFFFu) * 64 + lane];
        unsigned b2 = ebf[(long)(p2 & 0x1FFFFu) * 64 + lane];
        unsigned b3 = ebf[(long)(p3 & 0x1FFFFu) * 64 + lane];
        float v0 = __uint_as_float(p0 & 0xFFFE0000u);
        float v1 = __uint_as_float(p1 & 0xFFFE0000u);
        float v2 = __uint_as_float(p2 & 0xFFFE0000u);
        float v3 = __uint_as_float(p3 & 0xFFFE0000u);
        ax += v0 * __uint_as_float(b0 << 16) + v1 * __uint_as_float(b1 << 16)
            + v2 * __uint_as_float(b2 << 16) + v3 * __uint_as_float(b3 << 16);
        ay += v0 * __uint_as_float(b0 & 0xffff0000u) + v1 * __uint_as_float(b1 & 0xffff0000u)
            + v2 * __uint_as_float(b2 & 0xffff0000u) + v3 * __uint_as_float(b3 & 0xffff0000u);
    }
    for (; j < e; ++j) {
        unsigned p = csr[j];
        unsigned b = ebf[(long)(p & 0x1FFFFu) * 64 + lane];
        float v = __uint_as_float(p & 0xFFFE0000u);
        ax += v * __uint_as_float(b << 16);
        ay += v * __uint_as_float(b & 0xffff0000u);
    }
    float2 es = emb2[(long)x[n] * 64 + lane];   // f32 row: exact residual + e-output
    out2[(long)n * 128 + lane] = es;
    float2 m1;
    m1.x = ax + es.x;
    m1.y = ay + es.y;
    out2[(long)n * 128 + 64 + lane] = m1;
}

// ---------------- FC + dropout + leaky_relu ----------------
__global__ __launch_bounds__(256) void fc_kernel(float* __restrict__ out,
                                                 const float* __restrict__ fc_w,
                                                 const float* __restrict__ fc_b) {
    __shared__ float wt[128][132];
    __shared__ float ms[32][128];
    int tid = threadIdx.x;
    int row0 = blockIdx.x * 32;

    for (int i = tid; i < 128 * 128; i += 256) {
        int j = i >> 7, k = i & 127;
        wt[k][j] = fc_w[i];
    }
    for (int i = tid; i < 32 * 32; i += 256) {
        int r = i >> 5, q = i & 31;
        long n = row0 + r;
        float4 v = *(const float4*)(out + n * 256 + 128 + q * 4);
        unsigned base = (unsigned)n * 128u + (unsigned)(q * 4);
        float* vp = reinterpret_cast<float*>(&v);
#pragma unroll
        for (int c = 0; c < 4; ++c)
            vp[c] = keep_elem(base + c) ? vp[c] * (1.0f / 0.9f) : 0.0f;
        *(float4*)(&ms[r][q * 4]) = v;
    }
    __syncthreads();

    int rg = tid >> 5;
    int cg = tid & 31;
    float acc[4][4] = {{0.f}};
    for (int k = 0; k < 128; ++k) {
        float4 w4 = *(const float4*)(&wt[k][cg * 4]);
#pragma unroll
        for (int r = 0; r < 4; ++r) {
            float m = ms[rg * 4 + r][k];
            acc[r][0] += m * w4.x;
            acc[r][1] += m * w4.y;
            acc[r][2] += m * w4.z;
            acc[r][3] += m * w4.w;
        }
    }

    float4 b4 = *(const float4*)(fc_b + cg * 4);
#pragma unroll
    for (int r = 0; r < 4; ++r) {
        long n = row0 + rg * 4 + r;
        float4 o;
        o.x = acc[r][0] + b4.x;
        o.y = acc[r][1] + b4.y;
        o.z = acc[r][2] + b4.z;
        o.w = acc[r][3] + b4.w;
        o.x = o.x >= 0.f ? o.x : 0.2f * o.x;
        o.y = o.y >= 0.f ? o.y : 0.2f * o.y;
        o.z = o.z >= 0.f ? o.z : 0.2f * o.z;
        o.w = o.w >= 0.f ? o.w : 0.2f * o.w;
        *(float4*)(out + n * 256 + 128 + cg * 4) = o;
    }
}

// ---------------- R1 atomic fallback (ws too small) ----------------
__global__ __launch_bounds__(256) void init_kernel(const int* __restrict__ x,
                                                   const float4* __restrict__ emb4,
                                                   float4* __restrict__ out4) {
    int i = blockIdx.x * 256 + threadIdx.x;
    int n = i >> 5;
    int q = i & 31;
    if (n >= NN) return;
    float4 v = emb4[(long)x[n] * 32 + q];
    out4[(long)n * 64 + q] = v;
    out4[(long)n * 64 + 32 + q] = v;
}

#define EDGES_PER_GROUP 8
__global__ __launch_bounds__(256) void scatter_kernel(const int* __restrict__ x,
                                                      const int* __restrict__ row,
                                                      const int* __restrict__ col,
                                                      const float* __restrict__ vals,
                                                      const float4* __restrict__ emb4,
                                                      float* __restrict__ out) {
    long gid = (long)blockIdx.x * 256 + threadIdx.x;
    long group = gid >> 5;
    int lane = (int)(gid & 31);
    long e0 = group * EDGES_PER_GROUP;
#pragma unroll
    for (int k = 0; k < EDGES_PER_GROUP; ++k) {
        long e = e0 + k;
        if (e >= EE) break;
        int r = row[e];
        int c = col[e];
        float v = vals[e];
        float4 ev = emb4[(long)x[c] * 32 + lane];
        float* dst = out + (long)r * 256 + 128 + lane * 4;
        atomicAdd(dst + 0, v * ev.x);
        atomicAdd(dst + 1, v * ev.y);
        atomicAdd(dst + 2, v * ev.z);
        atomicAdd(dst + 3, v * ev.w);
    }
}

extern "C" void kernel_launch(void* const* d_in, const int* in_sizes, int n_in,
                              void* d_out, int out_size, void* d_ws, size_t ws_size,
                              hipStream_t stream) {
    const int*   x    = (const int*)d_in[0];
    const int*   row  = (const int*)d_in[1];
    const int*   col  = (const int*)d_in[2];
    const float* vals = (const float*)d_in[3];
    const float* emb  = (const float*)d_in[4];
    const float* fc_w = (const float*)d_in[5];
    const float* fc_b = (const float*)d_in[6];
    float* out = (float*)d_out;

    size_t off = 0;
    char* ws = (char*)d_ws;
    int* counts = (int*)(ws + off); off += (((size_t)NN * 4) + 255) & ~(size_t)255;
    int* rowptr = (int*)(ws + off); off += (((size_t)(NN + 1) * 4) + 255) & ~(size_t)255;
    int* bsums  = (int*)(ws + off); off += 4096;
    unsigned* csr = (unsigned*)(ws + off); off += (size_t)EE * 4;
    int* rank   = (int*)(ws + off); off += (size_t)EE * 4;
    unsigned* ebf = (unsigned*)(ws + off); off += (size_t)NN * DD * 2;
    size_t need = off;   // 52,004,608 B — identical to R3's proven-satisfied layout

    if (ws_size >= need) {
        setup_kernel<<<(int)(((long)NN * DD / 4 + 255) / 256), 256, 0, stream>>>(
            (const float4*)emb, (uint2*)ebf, (int4*)counts);
        hist_kernel<<<EE / 4 / 256, 256, 0, stream>>>((const int4*)row, counts, (int4*)rank);
        scan1_kernel<<<NBLK, SCAN_B, 0, stream>>>(counts, rowptr, bsums);
        scan2_kernel<<<1, 512, 0, stream>>>(bsums);
        scan3_kernel<<<NBLK, SCAN_B, 0, stream>>>(rowptr, bsums);
        fill_kernel<<<EE / 4 / 256, 256, 0, stream>>>(x, (const int4*)row, (const int4*)col,
                                                      (const float4*)vals, (const int4*)rank,
                                                      rowptr, csr);
        gather_kernel<<<NN / 4, 256, 0, stream>>>(x, rowptr, csr, ebf,
                                                  (const float2*)emb, (float2*)out);
    } else {
        init_kernel<<<(NN * 32 + 255) / 256, 256, 0, stream>>>(x, (const float4*)emb, (float4*)out);
        int scatter_blocks = (int)(((long)EE / EDGES_PER_GROUP) * 32 / 256);
        scatter_kernel<<<scatter_blocks, 256, 0, stream>>>(x, row, col, vals,
                                                           (const float4*)emb, out);
    }

    fc_kernel<<<NN / 32, 256, 0, stream>>>(out, fc_w, fc_b);
}

// Round 5
// 590.805 us; speedup vs baseline: 9.5360x; 1.1152x over previous
//
#include <hip/hip_runtime.h>

// DHCF layer: e = embed_w[x]; agg = segment_sum(vals * e[col] -> row);
// m1 = dropout(agg + e, jax threefry key(42), keep=0.9);
// x1 = leaky_relu(m1 @ fc_w.T + fc_b, 0.2); out = concat(e, x1), [N, 256] f32.
//
// R5: fc was occupancy-starved (84KB LDS -> 1 blk/CU) + threefry-serialized.
// (a) dropout moved into gather (hides under mem stalls; m1 stored post-dropout);
// (b) fc3: 64 rows x 128 j, transposed ms_t + 32-k-chunked w, 50.7KB LDS -> 3 blk/CU.

#define NN 100000
#define DD 128
#define EE 3200000
#define SCAN_B 256
#define NBLK ((NN + SCAN_B - 1) / SCAN_B)   // 391

__device__ __forceinline__ unsigned rotl32(unsigned v, int s) {
    return (v << s) | (v >> (32 - s));
}

// JAX threefry2x32, partitionable mode: block (0, idx), key (0, 42),
// bits = out0 ^ out1; u = bitcast((bits>>9)|0x3f800000)-1; keep = u < 0.9.
__device__ __forceinline__ bool keep_elem(unsigned idx) {
    unsigned x0 = 0u, x1 = idx;
    const unsigned k0 = 0u, k1 = 42u;
    const unsigned k2 = 0x1BD11BDAu ^ k0 ^ k1;
    x0 += k0; x1 += k1;
#define TFROUND(s) x0 += x1; x1 = rotl32(x1, s); x1 ^= x0;
    TFROUND(13) TFROUND(15) TFROUND(26) TFROUND(6)
    x0 += k1; x1 += k2 + 1u;
    TFROUND(17) TFROUND(29) TFROUND(16) TFROUND(24)
    x0 += k2; x1 += k0 + 2u;
    TFROUND(13) TFROUND(15) TFROUND(26) TFROUND(6)
    x0 += k0; x1 += k1 + 3u;
    TFROUND(17) TFROUND(29) TFROUND(16) TFROUND(24)
    x0 += k1; x1 += k2 + 4u;
    TFROUND(13) TFROUND(15) TFROUND(26) TFROUND(6)
    x0 += k2; x1 += k0 + 5u;
#undef TFROUND
    unsigned bits = x0 ^ x1;
    float u = __uint_as_float((bits >> 9) | 0x3f800000u) - 1.0f;
    return u < 0.9f;
}

// ---------------- setup: zero counts + f32->bf16 table convert ----------------
__global__ __launch_bounds__(256) void setup_kernel(const float4* __restrict__ emb4,
                                                    uint2* __restrict__ ebf2,
                                                    int4* __restrict__ counts4) {
    int i = blockIdx.x * 256 + threadIdx.x;          // 3.2M threads
    float4 v = emb4[i];
    unsigned a = __float_as_uint(v.x), b = __float_as_uint(v.y);
    unsigned c = __float_as_uint(v.z), d = __float_as_uint(v.w);
    a = (a + 0x7fffu + ((a >> 16) & 1u)) >> 16;
    b = (b + 0x7fffu + ((b >> 16) & 1u)) >> 16;
    c = (c + 0x7fffu + ((c >> 16) & 1u)) >> 16;
    d = (d + 0x7fffu + ((d >> 16) & 1u)) >> 16;
    uint2 o;
    o.x = a | (b << 16);
    o.y = c | (d << 16);
    ebf2[i] = o;
    if (i < NN / 4) counts4[i] = make_int4(0, 0, 0, 0);
}

// ---------------- hist: degree count + per-edge rank (ILP-4) ----------------
__global__ __launch_bounds__(256) void hist_kernel(const int4* __restrict__ row4,
                                                   int* __restrict__ counts,
                                                   int4* __restrict__ rank4) {
    int i = blockIdx.x * 256 + threadIdx.x;          // 800k threads (EE/4)
    int4 r = row4[i];
    int4 k;
    k.x = atomicAdd(&counts[r.x], 1);
    k.y = atomicAdd(&counts[r.y], 1);
    k.z = atomicAdd(&counts[r.z], 1);
    k.w = atomicAdd(&counts[r.w], 1);
    rank4[i] = k;
}

// per-256-block inclusive scan of counts -> rowptr[i+1]; block sums out.
__global__ __launch_bounds__(SCAN_B) void scan1_kernel(const int* __restrict__ counts,
                                                       int* __restrict__ rowptr,
                                                       int* __restrict__ bsums) {
    __shared__ int s[SCAN_B];
    int t = threadIdx.x;
    int i = blockIdx.x * SCAN_B + t;
    int v = (i < NN) ? counts[i] : 0;
    s[t] = v;
    __syncthreads();
    for (int d = 1; d < SCAN_B; d <<= 1) {
        int a = (t >= d) ? s[t - d] : 0;
        __syncthreads();
        s[t] += a;
        __syncthreads();
    }
    if (i < NN) rowptr[i + 1] = s[t];
    if (t == SCAN_B - 1) bsums[blockIdx.x] = s[t];
}

// exclusive scan of the 391 block sums: excl = incl - own.
__global__ __launch_bounds__(512) void scan2_kernel(int* __restrict__ bsums) {
    __shared__ int s[512];
    int t = threadIdx.x;
    int v = (t < NBLK) ? bsums[t] : 0;
    s[t] = v;
    __syncthreads();
    for (int d = 1; d < 512; d <<= 1) {
        int a = (t >= d) ? s[t - d] : 0;
        __syncthreads();
        s[t] += a;
        __syncthreads();
    }
    if (t < NBLK) bsums[t] = s[t] - v;
}

__global__ __launch_bounds__(SCAN_B) void scan3_kernel(int* __restrict__ rowptr,
                                                       const int* __restrict__ bsums) {
    int i = blockIdx.x * SCAN_B + threadIdx.x;
    if (i < NN) rowptr[i + 1] += bsums[i >> 8];
    if (i == 0) rowptr[0] = 0;
}

// ---------------- fill: atomic-free scattered pack-store (ILP-4) ----------------
__device__ __forceinline__ unsigned pack_entry(int xc, float v) {
    unsigned pb = __float_as_uint(v) + 0x10000u;     // round-half-up at bit 17
    return (pb & 0xFFFE0000u) | (unsigned)xc;
}

__global__ __launch_bounds__(256) void fill_kernel(const int* __restrict__ x,
                                                   const int4* __restrict__ row4,
                                                   const int4* __restrict__ col4,
                                                   const float4* __restrict__ vals4,
                                                   const int4* __restrict__ rank4,
                                                   const int* __restrict__ rowptr,
                                                   unsigned* __restrict__ csr) {
    int i = blockIdx.x * 256 + threadIdx.x;          // 800k threads
    int4 r = row4[i];
    int4 c = col4[i];
    float4 v = vals4[i];
    int4 k = rank4[i];
    csr[rowptr[r.x] + k.x] = pack_entry(x[c.x], v.x);
    csr[rowptr[r.y] + k.y] = pack_entry(x[c.y], v.y);
    csr[rowptr[r.z] + k.z] = pack_entry(x[c.z], v.z);
    csr[rowptr[r.w] + k.w] = pack_entry(x[c.w], v.w);
}

// ---------------- pull gather + DROPOUT: one wave per row ----------------
__global__ __launch_bounds__(256) void gather_kernel(const int* __restrict__ x,
                                                     const int* __restrict__ rowptr,
                                                     const unsigned* __restrict__ csr,
                                                     const unsigned* __restrict__ ebf,
                                                     const float2* __restrict__ emb2,
                                                     float2* __restrict__ out2) {
    int wave = threadIdx.x >> 6;
    int lane = threadIdx.x & 63;
    int n = blockIdx.x * 4 + wave;
    int s = rowptr[n], e = rowptr[n + 1];
    float ax = 0.f, ay = 0.f;
    int j = s;
    for (; j + 4 <= e; j += 4) {
        unsigned p0 = csr[j], p1 = csr[j + 1], p2 = csr[j + 2], p3 = csr[j + 3];
        unsigned b0 = ebf[(long)(p0 & 0x1FFFFu) * 64 + lane];
        unsigned b1 = ebf[(long)(p1 & 0x1FFFFu) * 64 + lane];
        unsigned b2 = ebf[(long)(p2 & 0x1FFFFu) * 64 + lane];
        unsigned b3 = ebf[(long)(p3 & 0x1FFFFu) * 64 + lane];
        float v0 = __uint_as_float(p0 & 0xFFFE0000u);
        float v1 = __uint_as_float(p1 & 0xFFFE0000u);
        float v2 = __uint_as_float(p2 & 0xFFFE0000u);
        float v3 = __uint_as_float(p3 & 0xFFFE0000u);
        ax += v0 * __uint_as_float(b0 << 16) + v1 * __uint_as_float(b1 << 16)
            + v2 * __uint_as_float(b2 << 16) + v3 * __uint_as_float(b3 << 16);
        ay += v0 * __uint_as_float(b0 & 0xffff0000u) + v1 * __uint_as_float(b1 & 0xffff0000u)
            + v2 * __uint_as_float(b2 & 0xffff0000u) + v3 * __uint_as_float(b3 & 0xffff0000u);
    }
    for (; j < e; ++j) {
        unsigned p = csr[j];
        unsigned b = ebf[(long)(p & 0x1FFFFu) * 64 + lane];
        float v = __uint_as_float(p & 0xFFFE0000u);
        ax += v * __uint_as_float(b << 16);
        ay += v * __uint_as_float(b & 0xffff0000u);
    }
    float2 es = emb2[(long)x[n] * 64 + lane];   // f32 row: exact residual + e-output
    out2[(long)n * 128 + lane] = es;
    float2 m1;
    m1.x = ax + es.x;
    m1.y = ay + es.y;
    unsigned base = (unsigned)n * 128u + 2u * (unsigned)lane;   // m1 flat index
    m1.x = keep_elem(base) ? m1.x * (1.0f / 0.9f) : 0.0f;
    m1.y = keep_elem(base + 1u) ? m1.y * (1.0f / 0.9f) : 0.0f;
    out2[(long)n * 128 + 64 + lane] = m1;       // post-dropout m1
}

// ---------------- fc3: 64 rows x 128 j, k-chunked w, NO dropout ----------------
// ms_t[k][row] (stride 66) -> broadcast reads; wc[kk][j] (stride 132) reloaded 4x.
__global__ __launch_bounds__(256, 3) void fc3_kernel(float* __restrict__ out,
                                                     const float* __restrict__ fc_w,
                                                     const float* __restrict__ fc_b) {
    __shared__ float ms_t[128][66];   // 33792 B
    __shared__ float wc[32][132];     // 16896 B
    int tid = threadIdx.x;
    int row0 = blockIdx.x * 64;
    const float4* fcw4 = (const float4*)fc_w;
    const float4* out4c = (const float4*)out;

    // stage m1 (post-dropout) transposed: ms_t[k][nl]
    for (int chunk = tid; chunk < 64 * 32; chunk += 256) {
        int nl = chunk >> 5;         // 0..63
        int q = chunk & 31;          // float4 index over k
        int n = row0 + nl;
        float4 v = (n < NN) ? out4c[(long)n * 64 + 32 + q]
                            : make_float4(0.f, 0.f, 0.f, 0.f);
        ms_t[q * 4 + 0][nl] = v.x;
        ms_t[q * 4 + 1][nl] = v.y;
        ms_t[q * 4 + 2][nl] = v.z;
        ms_t[q * 4 + 3][nl] = v.w;
    }

    int cg = tid & 31;   // j = cg*4 .. cg*4+3
    int rg = tid >> 5;   // rows rg*8 .. rg*8+7
    float acc[8][4];
#pragma unroll
    for (int r = 0; r < 8; ++r)
#pragma unroll
        for (int c = 0; c < 4; ++c) acc[r][c] = 0.f;

    for (int ch = 0; ch < 4; ++ch) {
        __syncthreads();   // first: after m-stage; later: protect wc overwrite
        for (int chunk = tid; chunk < 128 * 8; chunk += 256) {
            int jj = chunk >> 3;     // 0..127
            int kq = chunk & 7;      // 8 float4 = 32 k
            float4 v = fcw4[jj * 32 + ch * 8 + kq];
            wc[kq * 4 + 0][jj] = v.x;
            wc[kq * 4 + 1][jj] = v.y;
            wc[kq * 4 + 2][jj] = v.z;
            wc[kq * 4 + 3][jj] = v.w;
        }
        __syncthreads();
        int kbase = ch * 32;
#pragma unroll
        for (int kk = 0; kk < 32; ++kk) {
            float4 w4 = *(const float4*)(&wc[kk][cg * 4]);
            int k = kbase + kk;
            float2 m01 = *(const float2*)(&ms_t[k][rg * 8 + 0]);
            float2 m23 = *(const float2*)(&ms_t[k][rg * 8 + 2]);
            float2 m45 = *(const float2*)(&ms_t[k][rg * 8 + 4]);
            float2 m67 = *(const float2*)(&ms_t[k][rg * 8 + 6]);
            float m[8] = {m01.x, m01.y, m23.x, m23.y, m45.x, m45.y, m67.x, m67.y};
#pragma unroll
            for (int r = 0; r < 8; ++r) {
                acc[r][0] += m[r] * w4.x;
                acc[r][1] += m[r] * w4.y;
                acc[r][2] += m[r] * w4.z;
                acc[r][3] += m[r] * w4.w;
            }
        }
    }

    float4 b4 = *(const float4*)(fc_b + cg * 4);
#pragma unroll
    for (int r = 0; r < 8; ++r) {
        int n = row0 + rg * 8 + r;
        if (n >= NN) break;
        float4 o;
        o.x = acc[r][0] + b4.x;
        o.y = acc[r][1] + b4.y;
        o.z = acc[r][2] + b4.z;
        o.w = acc[r][3] + b4.w;
        o.x = o.x >= 0.f ? o.x : 0.2f * o.x;
        o.y = o.y >= 0.f ? o.y : 0.2f * o.y;
        o.z = o.z >= 0.f ? o.z : 0.2f * o.z;
        o.w = o.w >= 0.f ? o.w : 0.2f * o.w;
        *(float4*)(out + (long)n * 256 + 128 + cg * 4) = o;
    }
}

// ---------------- fallback tiers (proven R1/R2 paths) ----------------
__global__ __launch_bounds__(256) void init_kernel(const int* __restrict__ x,
                                                   const float4* __restrict__ emb4,
                                                   float4* __restrict__ out4) {
    int i = blockIdx.x * 256 + threadIdx.x;
    int n = i >> 5;
    int q = i & 31;
    if (n >= NN) return;
    float4 v = emb4[(long)x[n] * 32 + q];
    out4[(long)n * 64 + q] = v;
    out4[(long)n * 64 + 32 + q] = v;
}

#define EDGES_PER_GROUP 8
__global__ __launch_bounds__(256) void scatter_kernel(const int* __restrict__ x,
                                                      const int* __restrict__ row,
                                                      const int* __restrict__ col,
                                                      const float* __restrict__ vals,
                                                      const float4* __restrict__ emb4,
                                                      float* __restrict__ out) {
    long gid = (long)blockIdx.x * 256 + threadIdx.x;
    long group = gid >> 5;
    int lane = (int)(gid & 31);
    long e0 = group * EDGES_PER_GROUP;
#pragma unroll
    for (int k = 0; k < EDGES_PER_GROUP; ++k) {
        long e = e0 + k;
        if (e >= EE) break;
        int r = row[e];
        int c = col[e];
        float v = vals[e];
        float4 ev = emb4[(long)x[c] * 32 + lane];
        float* dst = out + (long)r * 256 + 128 + lane * 4;
        atomicAdd(dst + 0, v * ev.x);
        atomicAdd(dst + 1, v * ev.y);
        atomicAdd(dst + 2, v * ev.z);
        atomicAdd(dst + 3, v * ev.w);
    }
}

// old fc (with in-kernel dropout) for the atomic fallback tier
__global__ __launch_bounds__(256) void fc_kernel(float* __restrict__ out,
                                                 const float* __restrict__ fc_w,
                                                 const float* __restrict__ fc_b) {
    __shared__ float wt[128][132];
    __shared__ float ms[32][128];
    int tid = threadIdx.x;
    int row0 = blockIdx.x * 32;

    for (int i = tid; i < 128 * 128; i += 256) {
        int j = i >> 7, k = i & 127;
        wt[k][j] = fc_w[i];
    }
    for (int i = tid; i < 32 * 32; i += 256) {
        int r = i >> 5, q = i & 31;
        long n = row0 + r;
        float4 v = *(const float4*)(out + n * 256 + 128 + q * 4);
        unsigned base = (unsigned)n * 128u + (unsigned)(q * 4);
        float* vp = reinterpret_cast<float*>(&v);
#pragma unroll
        for (int c = 0; c < 4; ++c)
            vp[c] = keep_elem(base + c) ? vp[c] * (1.0f / 0.9f) : 0.0f;
        *(float4*)(&ms[r][q * 4]) = v;
    }
    __syncthreads();

    int rg = tid >> 5;
    int cg = tid & 31;
    float acc[4][4] = {{0.f}};
    for (int k = 0; k < 128; ++k) {
        float4 w4 = *(const float4*)(&wt[k][cg * 4]);
#pragma unroll
        for (int r = 0; r < 4; ++r) {
            float m = ms[rg * 4 + r][k];
            acc[r][0] += m * w4.x;
            acc[r][1] += m * w4.y;
            acc[r][2] += m * w4.z;
            acc[r][3] += m * w4.w;
        }
    }

    float4 b4 = *(const float4*)(fc_b + cg * 4);
#pragma unroll
    for (int r = 0; r < 4; ++r) {
        long n = row0 + rg * 4 + r;
        float4 o;
        o.x = acc[r][0] + b4.x;
        o.y = acc[r][1] + b4.y;
        o.z = acc[r][2] + b4.z;
        o.w = acc[r][3] + b4.w;
        o.x = o.x >= 0.f ? o.x : 0.2f * o.x;
        o.y = o.y >= 0.f ? o.y : 0.2f * o.y;
        o.z = o.z >= 0.f ? o.z : 0.2f * o.z;
        o.w = o.w >= 0.f ? o.w : 0.2f * o.w;
        *(float4*)(out + n * 256 + 128 + cg * 4) = o;
    }
}

extern "C" void kernel_launch(void* const* d_in, const int* in_sizes, int n_in,
                              void* d_out, int out_size, void* d_ws, size_t ws_size,
                              hipStream_t stream) {
    const int*   x    = (const int*)d_in[0];
    const int*   row  = (const int*)d_in[1];
    const int*   col  = (const int*)d_in[2];
    const float* vals = (const float*)d_in[3];
    const float* emb  = (const float*)d_in[4];
    const float* fc_w = (const float*)d_in[5];
    const float* fc_b = (const float*)d_in[6];
    float* out = (float*)d_out;

    size_t off = 0;
    char* ws = (char*)d_ws;
    int* counts = (int*)(ws + off); off += (((size_t)NN * 4) + 255) & ~(size_t)255;
    int* rowptr = (int*)(ws + off); off += (((size_t)(NN + 1) * 4) + 255) & ~(size_t)255;
    int* bsums  = (int*)(ws + off); off += 4096;
    unsigned* csr = (unsigned*)(ws + off); off += (size_t)EE * 4;
    int* rank   = (int*)(ws + off); off += (size_t)EE * 4;
    unsigned* ebf = (unsigned*)(ws + off); off += (size_t)NN * DD * 2;
    size_t need = off;   // 52,004,608 B — proven satisfied in R3/R4

    if (ws_size >= need) {
        setup_kernel<<<(int)(((long)NN * DD / 4 + 255) / 256), 256, 0, stream>>>(
            (const float4*)emb, (uint2*)ebf, (int4*)counts);
        hist_kernel<<<EE / 4 / 256, 256, 0, stream>>>((const int4*)row, counts, (int4*)rank);
        scan1_kernel<<<NBLK, SCAN_B, 0, stream>>>(counts, rowptr, bsums);
        scan2_kernel<<<1, 512, 0, stream>>>(bsums);
        scan3_kernel<<<NBLK, SCAN_B, 0, stream>>>(rowptr, bsums);
        fill_kernel<<<EE / 4 / 256, 256, 0, stream>>>(x, (const int4*)row, (const int4*)col,
                                                      (const float4*)vals, (const int4*)rank,
                                                      rowptr, csr);
        gather_kernel<<<NN / 4, 256, 0, stream>>>(x, rowptr, csr, ebf,
                                                  (const float2*)emb, (float2*)out);
        fc3_kernel<<<(NN + 63) / 64, 256, 0, stream>>>(out, fc_w, fc_b);
    } else {
        init_kernel<<<(NN * 32 + 255) / 256, 256, 0, stream>>>(x, (const float4*)emb, (float4*)out);
        int scatter_blocks = (int)(((long)EE / EDGES_PER_GROUP) * 32 / 256);
        scatter_kernel<<<scatter_blocks, 256, 0, stream>>>(x, row, col, vals,
                                                           (const float4*)emb, out);
        fc_kernel<<<NN / 32, 256, 0, stream>>>(out, fc_w, fc_b);
    }
}